// Round 10
// baseline (190.935 us; speedup 1.0000x reference)
//
#include <hip/hip_runtime.h>
#include <hip/hip_bf16.h>

#define NH 12
#define HD 64
#define NB 4
#define SEQ 2048
#define NP 768
#define LOG2E 1.44269504f
#define MASK_L2 14426.9504f   // 10000 * log2(e)

typedef __bf16 bf16x8 __attribute__((ext_vector_type(8)));
typedef float f32x4 __attribute__((ext_vector_type(4)));
typedef float f32x16 __attribute__((ext_vector_type(16)));
typedef unsigned u32x4 __attribute__((ext_vector_type(4)));

static __device__ __forceinline__ bf16x8 load_bf16x8(const __bf16* p) {
    return *reinterpret_cast<const bf16x8*>(p);
}
static __device__ __forceinline__ float hw_exp2(float x) {
    return __builtin_amdgcn_exp2f(x);
}
static __device__ __forceinline__ unsigned pack_bf16(float lo, float hi) {
    unsigned a = (unsigned)__builtin_bit_cast(unsigned short, (__bf16)lo);
    unsigned b = (unsigned)__builtin_bit_cast(unsigned short, (__bf16)hi);
    return a | (b << 16);
}

// ---------------------------------------------------------------------------
// Kernel 1 v9: QKV projection (W transpose fused). Same as v8 except Vf is
// written in the SIGMA-PERMUTED key order sigma(8*hi+j) = (j&3)+8*(j>>2)+4*hi
// matching the S^T C-layout, so flash needs NO cross-lane exchange for PV.
//   Q : row-major (bh, t, d)
//   Kf: per 64-key block [bh][kb64][frag 2*dstep+keyhalf][lane][8]
//   Vf: per 64-key block [bh][kb64][frag 2*keychunk+dhalf][lane][8], permuted
// ---------------------------------------------------------------------------
__global__ __launch_bounds__(256) void qkv_kernel(
    const float* __restrict__ hidden,
    const float* __restrict__ Wq, const float* __restrict__ Wk,
    const float* __restrict__ Wv,
    const float* __restrict__ bq, const float* __restrict__ bk,
    const float* __restrict__ bv,
    __bf16* __restrict__ Qw, __bf16* __restrict__ Kf, __bf16* __restrict__ Vf)
{
    __shared__ __bf16 wtileT[64][72];   // [c][k]
    __shared__ __bf16 ot[64][72];       // [t][c]

    const int tid  = threadIdx.x;
    const int lane = tid & 63;
    const int w    = tid >> 6;
    const int g    = lane >> 4;
    const int n    = lane & 15;
    const int n32  = lane & 31;
    const int hi   = lane >> 5;

    const int row0 = blockIdx.x * 64;
    const int gi   = blockIdx.y;          // 0..5
    const int b_   = row0 >> 11;
    const int t0   = row0 & (SEQ - 1);
    const int kb64 = t0 >> 6;

    const float* hrow = hidden + (size_t)(row0 + w * 16 + n) * HD + 8 * g;
    f32x4 h0 = *(const f32x4*)(hrow);
    f32x4 h1 = *(const f32x4*)(hrow + 4);
    f32x4 h2 = *(const f32x4*)(hrow + 32);
    f32x4 h3 = *(const f32x4*)(hrow + 36);
    bf16x8 a0, a1;
    #pragma unroll
    for (int j = 0; j < 4; ++j) {
        a0[j]     = (__bf16)h0[j];
        a0[j + 4] = (__bf16)h1[j];
        a1[j]     = (__bf16)h2[j];
        a1[j + 4] = (__bf16)h3[j];
    }

    const int dr   = tid >> 2;        // 0..63 (W row = k)
    const int coff = (tid & 3) * 16;  // 16 consecutive cols

    for (int tt = 0; tt < 6; ++tt) {
        const int tile_id = gi * 6 + tt;       // 0..35
        const int proj    = tile_id / 12;
        const int head    = tile_id % 12;
        const int bh      = b_ * NH + head;
        const float* W    = proj == 0 ? Wq : (proj == 1 ? Wk : Wv);
        const float* bias = proj == 0 ? bq : (proj == 1 ? bk : bv);
        const float qs    = (proj == 0) ? 0.125f * LOG2E : 1.0f;

        const float* wr = W + (size_t)dr * NP + head * 64 + coff;
        f32x4 x0 = *(const f32x4*)(wr);
        f32x4 x1 = *(const f32x4*)(wr + 4);
        f32x4 x2 = *(const f32x4*)(wr + 8);
        f32x4 x3 = *(const f32x4*)(wr + 12);
        #pragma unroll
        for (int i = 0; i < 4; ++i) {
            wtileT[coff + i     ][dr] = (__bf16)(x0[i] * qs);
            wtileT[coff + 4 + i ][dr] = (__bf16)(x1[i] * qs);
            wtileT[coff + 8 + i ][dr] = (__bf16)(x2[i] * qs);
            wtileT[coff + 12 + i][dr] = (__bf16)(x3[i] * qs);
        }
        __syncthreads();   // wtileT ready; also fences prev tile's ot reads

        #pragma unroll
        for (int dt = 0; dt < 4; ++dt) {
            const bf16x8 b0 = *(const bf16x8*)&wtileT[dt * 16 + n][8 * g];
            const bf16x8 b1 = *(const bf16x8*)&wtileT[dt * 16 + n][32 + 8 * g];
            f32x4 acc = {0.f, 0.f, 0.f, 0.f};
            acc = __builtin_amdgcn_mfma_f32_16x16x32_bf16(a0, b0, acc, 0, 0, 0);
            acc = __builtin_amdgcn_mfma_f32_16x16x32_bf16(a1, b1, acc, 0, 0, 0);
            const float bb = bias[head * 64 + dt * 16 + n] * qs;
            #pragma unroll
            for (int r = 0; r < 4; ++r)
                ot[w * 16 + 4 * g + r][dt * 16 + n] = (__bf16)(acc[r] + bb);
        }
        __syncthreads();   // ot complete; wtileT frag reads done

        if (proj == 0) {
            __bf16* dst = Qw + ((size_t)bh * SEQ + t0 + w * 16) * HD;
            const int tr = lane >> 2;
            const int d0 = (lane & 3) * 16;
            *(bf16x8*)(dst + (size_t)tr * HD + d0)     = *(const bf16x8*)&ot[w * 16 + tr][d0];
            *(bf16x8*)(dst + (size_t)tr * HD + d0 + 8) = *(const bf16x8*)&ot[w * 16 + tr][d0 + 8];
        } else if (proj == 1) {
            // Kf frag (dstep=w, sub): lane l = K[t0+sub*32+n32][w*16+8hi..+8]
            __bf16* base = Kf + (size_t)bh * SEQ * HD + (size_t)kb64 * 4096;
            #pragma unroll
            for (int sub = 0; sub < 2; ++sub) {
                const bf16x8 fr = *(const bf16x8*)&ot[sub * 32 + n32][w * 16 + 8 * hi];
                *(bf16x8*)(base + (size_t)(w * 2 + sub) * 512 + lane * 8) = fr;
            }
        } else {
            // Vf frag (keychunk=w, dsub): SIGMA-permuted key order so the
            // S^T C-layout regs feed PV directly (no lane exchange in flash)
            __bf16* base = Vf + (size_t)bh * SEQ * HD + (size_t)kb64 * 4096;
            #pragma unroll
            for (int dsub = 0; dsub < 2; ++dsub) {
                bf16x8 v;
                #pragma unroll
                for (int j = 0; j < 8; ++j)
                    v[j] = ot[w * 16 + ((j & 3) + 8 * (j >> 2) + 4 * hi)][dsub * 32 + n32];
                *(bf16x8*)(base + (size_t)(w * 2 + dsub) * 512 + lane * 8) = v;
            }
        }
    }
}

// ---------------------------------------------------------------------------
// Kernel 2 v9: key-split flash, zero cross-lane ops in the loop.
// Block = 32 q; wave w owns keys [w*512, w*512+512) in 8 x 64-key iters.
// Per iter: 8 S + 2 mask MFMAs, 32 exp2, 16 packs (B-frags direct from own
// regs via the sigma-permuted Vf), 4 lsum MFMAs (A=ones), 8 PV MFMAs.
// launch_bounds (256,2): 256-VGPR budget keeps sa/sb out of AGPRs.
// ---------------------------------------------------------------------------
__global__ __launch_bounds__(256, 2) void flash_attn_kernel(
    const __bf16* __restrict__ Qw, const __bf16* __restrict__ Kf,
    const __bf16* __restrict__ Vf, const float* __restrict__ amask,
    float* __restrict__ out)
{
    __shared__ __align__(16) float et[4][32][68];   // per-wave O^T partials
    __shared__ float lrow[4][32];
    __shared__ __bf16 mdd[SEQ];

    const int tid  = threadIdx.x;
    const int lane = tid & 63;
    const int w    = tid >> 6;
    const int n32  = lane & 31;
    const int hi   = lane >> 5;

    const int bid    = blockIdx.x;        // 3072
    const int xcd    = bid & 7;
    const int slot   = bid >> 3;          // 0..383
    const int bh     = xcd * 6 + (slot >> 6);
    const int qchunk = slot & 63;
    const int b_     = bh / NH;
    const int h      = bh % NH;
    const int q0     = qchunk * 32;

    // per-wave mdd slice (same-wave RAW: no barrier needed)
    const float* mp = amask + (size_t)b_ * SEQ;
    #pragma unroll
    for (int i = 0; i < 8; ++i) {
        const int idx = w * 512 + i * 64 + lane;
        mdd[idx] = (__bf16)fmaf(mp[idx], MASK_L2, -MASK_L2);
    }

    // Q as B-operand: B[k=16*dstep+8*hi+j][q=n32]
    const __bf16* Qrow = Qw + ((size_t)bh * SEQ + q0 + n32) * HD + 8 * hi;
    bf16x8 qf[4];
    #pragma unroll
    for (int d = 0; d < 4; ++d) qf[d] = load_bf16x8(Qrow + d * 16);

    bf16x8 qone, aones;
    #pragma unroll
    for (int j = 0; j < 8; ++j) { qone[j] = (__bf16)0.0f; aones[j] = (__bf16)1.0f; }
    if (hi == 0) qone[0] = (__bf16)1.0f;   // B[k=0][q] = 1

    const __bf16* kfb_ = Kf + (size_t)bh * SEQ * HD + (size_t)lane * 8;
    const __bf16* vfb_ = Vf + (size_t)bh * SEQ * HD + (size_t)lane * 8;

    f32x16 o0   = {0,0,0,0,0,0,0,0,0,0,0,0,0,0,0,0};
    f32x16 o1   = {0,0,0,0,0,0,0,0,0,0,0,0,0,0,0,0};
    f32x16 lacc = {0,0,0,0,0,0,0,0,0,0,0,0,0,0,0,0};

    const int kstart = w * 512;
    #pragma unroll 2
    for (int it = 0; it < 8; ++it) {
        const int kb = kstart + it * 64;
        const size_t foff = (size_t)(kb >> 6) * 4096;

        bf16x8 kfa[4], kfb[4];
        #pragma unroll
        for (int d = 0; d < 4; ++d) {
            kfa[d] = load_bf16x8(kfb_ + foff + (size_t)(2 * d) * 512);
            kfb[d] = load_bf16x8(kfb_ + foff + (size_t)(2 * d + 1) * 512);
        }
        bf16x8 vf0[4], vf1[4];
        #pragma unroll
        for (int c = 0; c < 4; ++c) {
            vf0[c] = load_bf16x8(vfb_ + foff + (size_t)(2 * c) * 512);
            vf1[c] = load_bf16x8(vfb_ + foff + (size_t)(2 * c + 1) * 512);
        }

        bf16x8 maa, mab;
        #pragma unroll
        for (int j = 0; j < 8; ++j) { maa[j] = (__bf16)0.0f; mab[j] = (__bf16)0.0f; }
        maa[0] = mdd[kb + n32];
        mab[0] = mdd[kb + 32 + n32];

        // S^T (log2 domain) + mask via rank-1 MFMA
        f32x16 sa = {0,0,0,0,0,0,0,0,0,0,0,0,0,0,0,0};
        f32x16 sb = {0,0,0,0,0,0,0,0,0,0,0,0,0,0,0,0};
        #pragma unroll
        for (int d = 0; d < 4; ++d) {
            sa = __builtin_amdgcn_mfma_f32_32x32x16_bf16(kfa[d], qf[d], sa, 0, 0, 0);
            sb = __builtin_amdgcn_mfma_f32_32x32x16_bf16(kfb[d], qf[d], sb, 0, 0, 0);
        }
        sa = __builtin_amdgcn_mfma_f32_32x32x16_bf16(maa, qone, sa, 0, 0, 0);
        sb = __builtin_amdgcn_mfma_f32_32x32x16_bf16(mab, qone, sb, 0, 0, 0);

        // exp2 + direct pack: reg r of each 8-reg group IS B-slot j=r (sigma
        // baked into Vf), so no cross-lane exchange is needed.
        bf16x8 P[4];
        #pragma unroll
        for (int half = 0; half < 2; ++half) {
            const f32x16& s = half ? sb : sa;
            float p[16];
            #pragma unroll
            for (int r = 0; r < 16; ++r) p[r] = hw_exp2(s[r]);
            u32x4 B0, B1;
            #pragma unroll
            for (int i = 0; i < 4; ++i) {
                B0[i] = pack_bf16(p[2 * i],     p[2 * i + 1]);
                B1[i] = pack_bf16(p[8 + 2 * i], p[8 + 2 * i + 1]);
            }
            P[2 * half]     = __builtin_bit_cast(bf16x8, B0);
            P[2 * half + 1] = __builtin_bit_cast(bf16x8, B1);
        }

        // l via MFMA (A=ones): permutation-invariant column sums
        lacc = __builtin_amdgcn_mfma_f32_32x32x16_bf16(aones, P[0], lacc, 0, 0, 0);
        lacc = __builtin_amdgcn_mfma_f32_32x32x16_bf16(aones, P[1], lacc, 0, 0, 0);
        lacc = __builtin_amdgcn_mfma_f32_32x32x16_bf16(aones, P[2], lacc, 0, 0, 0);
        lacc = __builtin_amdgcn_mfma_f32_32x32x16_bf16(aones, P[3], lacc, 0, 0, 0);

        #pragma unroll
        for (int c = 0; c < 4; ++c) {
            o0 = __builtin_amdgcn_mfma_f32_32x32x16_bf16(vf0[c], P[c], o0, 0, 0, 0);
            o1 = __builtin_amdgcn_mfma_f32_32x32x16_bf16(vf1[c], P[c], o1, 0, 0, 0);
        }
    }

    // stage per-wave partials, then cross-wave combine
    #pragma unroll
    for (int r = 0; r < 16; ++r) {
        const int dl = (r & 3) + 8 * (r >> 2) + 4 * hi;
        et[w][n32][dl]      = o0[r];
        et[w][n32][32 + dl] = o1[r];
    }
    if (lane < 32) lrow[w][n32] = lacc[0];   // full 512-key sum, every lane
    __syncthreads();

    const int q  = tid >> 3;
    const int d0 = (tid & 7) * 8;
    const float linv = 1.0f / (lrow[0][q] + lrow[1][q] + lrow[2][q] + lrow[3][q]);
    f32x4 acc0 = {0,0,0,0}, acc1 = {0,0,0,0};
    #pragma unroll
    for (int ww = 0; ww < 4; ++ww) {
        acc0 += *(const f32x4*)&et[ww][q][d0];
        acc1 += *(const f32x4*)&et[ww][q][d0 + 4];
    }
    float* orow = out + ((size_t)(b_ * SEQ + q0 + q)) * NP + h * HD + d0;
    f32x4 r0, r1;
    #pragma unroll
    for (int i = 0; i < 4; ++i) { r0[i] = acc0[i] * linv; r1[i] = acc1[i] * linv; }
    *(f32x4*)(orow)     = r0;
    *(f32x4*)(orow + 4) = r1;
}

extern "C" void kernel_launch(void* const* d_in, const int* in_sizes, int n_in,
                              void* d_out, int out_size, void* d_ws, size_t ws_size,
                              hipStream_t stream) {
    const float* hidden = (const float*)d_in[0];
    const float* amask  = (const float*)d_in[1];
    const float* Wq     = (const float*)d_in[2];
    const float* bq     = (const float*)d_in[3];
    const float* Wk     = (const float*)d_in[4];
    const float* bk     = (const float*)d_in[5];
    const float* Wv     = (const float*)d_in[6];
    const float* bv     = (const float*)d_in[7];
    float* out = (float*)d_out;

    const size_t elems = (size_t)NB * NH * SEQ * HD; // 6,291,456
    __bf16* Qw = (__bf16*)d_ws;
    __bf16* Kf = Qw + elems;
    __bf16* Vf = Kf + elems;

    qkv_kernel<<<dim3(128, 6), 256, 0, stream>>>(
        hidden, Wq, Wk, Wv, bq, bk, bv, Qw, Kf, Vf);

    flash_attn_kernel<<<dim3(3072), 256, 0, stream>>>(
        Qw, Kf, Vf, amask, out);
}

// Round 11
// 169.848 us; speedup vs baseline: 1.1242x; 1.1242x over previous
//
#include <hip/hip_runtime.h>
#include <hip/hip_bf16.h>

#define NH 12
#define HD 64
#define NB 4
#define SEQ 2048
#define NP 768
#define LOG2E 1.44269504f
#define MASK_L2 14426.9504f   // 10000 * log2(e)

typedef __bf16 bf16x8 __attribute__((ext_vector_type(8)));
typedef float f32x4 __attribute__((ext_vector_type(4)));
typedef float f32x16 __attribute__((ext_vector_type(16)));
typedef unsigned u32x4 __attribute__((ext_vector_type(4)));

static __device__ __forceinline__ bf16x8 load_bf16x8(const __bf16* p) {
    return *reinterpret_cast<const bf16x8*>(p);
}
static __device__ __forceinline__ float hw_exp2(float x) {
    return __builtin_amdgcn_exp2f(x);
}
static __device__ __forceinline__ unsigned pack_bf16(float lo, float hi) {
    unsigned a = (unsigned)__builtin_bit_cast(unsigned short, (__bf16)lo);
    unsigned b = (unsigned)__builtin_bit_cast(unsigned short, (__bf16)hi);
    return a | (b << 16);
}

// ---------------------------------------------------------------------------
// Kernel 1 (unchanged from v9): QKV projection, W transpose fused. Vf is
// written in SIGMA-PERMUTED key order sigma(8*hi+j) = (j&3)+8*(j>>2)+4*hi
// matching the S^T C-layout, so flash needs NO cross-lane exchange for PV.
//   Q : row-major (bh, t, d)
//   Kf: per 64-key block [bh][kb64][frag 2*dstep+keyhalf][lane][8]
//   Vf: per 64-key block [bh][kb64][frag 2*keychunk+dhalf][lane][8], permuted
// ---------------------------------------------------------------------------
__global__ __launch_bounds__(256) void qkv_kernel(
    const float* __restrict__ hidden,
    const float* __restrict__ Wq, const float* __restrict__ Wk,
    const float* __restrict__ Wv,
    const float* __restrict__ bq, const float* __restrict__ bk,
    const float* __restrict__ bv,
    __bf16* __restrict__ Qw, __bf16* __restrict__ Kf, __bf16* __restrict__ Vf)
{
    __shared__ __bf16 wtileT[64][72];   // [c][k]
    __shared__ __bf16 ot[64][72];       // [t][c]

    const int tid  = threadIdx.x;
    const int lane = tid & 63;
    const int w    = tid >> 6;
    const int g    = lane >> 4;
    const int n    = lane & 15;
    const int n32  = lane & 31;
    const int hi   = lane >> 5;

    const int row0 = blockIdx.x * 64;
    const int gi   = blockIdx.y;          // 0..5
    const int b_   = row0 >> 11;
    const int t0   = row0 & (SEQ - 1);
    const int kb64 = t0 >> 6;

    const float* hrow = hidden + (size_t)(row0 + w * 16 + n) * HD + 8 * g;
    f32x4 h0 = *(const f32x4*)(hrow);
    f32x4 h1 = *(const f32x4*)(hrow + 4);
    f32x4 h2 = *(const f32x4*)(hrow + 32);
    f32x4 h3 = *(const f32x4*)(hrow + 36);
    bf16x8 a0, a1;
    #pragma unroll
    for (int j = 0; j < 4; ++j) {
        a0[j]     = (__bf16)h0[j];
        a0[j + 4] = (__bf16)h1[j];
        a1[j]     = (__bf16)h2[j];
        a1[j + 4] = (__bf16)h3[j];
    }

    const int dr   = tid >> 2;        // 0..63 (W row = k)
    const int coff = (tid & 3) * 16;  // 16 consecutive cols

    for (int tt = 0; tt < 6; ++tt) {
        const int tile_id = gi * 6 + tt;       // 0..35
        const int proj    = tile_id / 12;
        const int head    = tile_id % 12;
        const int bh      = b_ * NH + head;
        const float* W    = proj == 0 ? Wq : (proj == 1 ? Wk : Wv);
        const float* bias = proj == 0 ? bq : (proj == 1 ? bk : bv);
        const float qs    = (proj == 0) ? 0.125f * LOG2E : 1.0f;

        const float* wr = W + (size_t)dr * NP + head * 64 + coff;
        f32x4 x0 = *(const f32x4*)(wr);
        f32x4 x1 = *(const f32x4*)(wr + 4);
        f32x4 x2 = *(const f32x4*)(wr + 8);
        f32x4 x3 = *(const f32x4*)(wr + 12);
        #pragma unroll
        for (int i = 0; i < 4; ++i) {
            wtileT[coff + i     ][dr] = (__bf16)(x0[i] * qs);
            wtileT[coff + 4 + i ][dr] = (__bf16)(x1[i] * qs);
            wtileT[coff + 8 + i ][dr] = (__bf16)(x2[i] * qs);
            wtileT[coff + 12 + i][dr] = (__bf16)(x3[i] * qs);
        }
        __syncthreads();   // wtileT ready; also fences prev tile's ot reads

        #pragma unroll
        for (int dt = 0; dt < 4; ++dt) {
            const bf16x8 b0 = *(const bf16x8*)&wtileT[dt * 16 + n][8 * g];
            const bf16x8 b1 = *(const bf16x8*)&wtileT[dt * 16 + n][32 + 8 * g];
            f32x4 acc = {0.f, 0.f, 0.f, 0.f};
            acc = __builtin_amdgcn_mfma_f32_16x16x32_bf16(a0, b0, acc, 0, 0, 0);
            acc = __builtin_amdgcn_mfma_f32_16x16x32_bf16(a1, b1, acc, 0, 0, 0);
            const float bb = bias[head * 64 + dt * 16 + n] * qs;
            #pragma unroll
            for (int r = 0; r < 4; ++r)
                ot[w * 16 + 4 * g + r][dt * 16 + n] = (__bf16)(acc[r] + bb);
        }
        __syncthreads();   // ot complete; wtileT frag reads done

        if (proj == 0) {
            __bf16* dst = Qw + ((size_t)bh * SEQ + t0 + w * 16) * HD;
            const int tr = lane >> 2;
            const int d0 = (lane & 3) * 16;
            *(bf16x8*)(dst + (size_t)tr * HD + d0)     = *(const bf16x8*)&ot[w * 16 + tr][d0];
            *(bf16x8*)(dst + (size_t)tr * HD + d0 + 8) = *(const bf16x8*)&ot[w * 16 + tr][d0 + 8];
        } else if (proj == 1) {
            // Kf frag (dstep=w, sub): lane l = K[t0+sub*32+n32][w*16+8hi..+8]
            __bf16* base = Kf + (size_t)bh * SEQ * HD + (size_t)kb64 * 4096;
            #pragma unroll
            for (int sub = 0; sub < 2; ++sub) {
                const bf16x8 fr = *(const bf16x8*)&ot[sub * 32 + n32][w * 16 + 8 * hi];
                *(bf16x8*)(base + (size_t)(w * 2 + sub) * 512 + lane * 8) = fr;
            }
        } else {
            // Vf frag (keychunk=w, dsub): sigma-permuted key order
            __bf16* base = Vf + (size_t)bh * SEQ * HD + (size_t)kb64 * 4096;
            #pragma unroll
            for (int dsub = 0; dsub < 2; ++dsub) {
                bf16x8 v;
                #pragma unroll
                for (int j = 0; j < 8; ++j)
                    v[j] = ot[w * 16 + ((j & 3) + 8 * (j >> 2) + 4 * hi)][dsub * 32 + n32];
                *(bf16x8*)(base + (size_t)(w * 2 + dsub) * 512 + lane * 8) = v;
            }
        }
    }
}

// ---------------------------------------------------------------------------
// Kernel 2 v10: v8's key-split flash (87.6 us, occupancy 27.9%) with ONLY the
// verified-good v9 change applied: sigma-permuted Vf -> direct pack, zero
// cross-lane ops in the loop. lsum stays scalar (18 MFMAs/iter not 22);
// launch_bounds stays (256,3); no unroll pragma (TLP hides L2 latency).
// ---------------------------------------------------------------------------
__global__ __launch_bounds__(256, 3) void flash_attn_kernel(
    const __bf16* __restrict__ Qw, const __bf16* __restrict__ Kf,
    const __bf16* __restrict__ Vf, const float* __restrict__ amask,
    float* __restrict__ out)
{
    __shared__ __align__(16) float et[4][32][68];   // per-wave O^T partials
    __shared__ float lrow[4][32];
    __shared__ __bf16 mdd[SEQ];

    const int tid  = threadIdx.x;
    const int lane = tid & 63;
    const int w    = tid >> 6;
    const int n32  = lane & 31;
    const int hi   = lane >> 5;

    const int bid    = blockIdx.x;        // 3072
    const int xcd    = bid & 7;
    const int slot   = bid >> 3;          // 0..383
    const int bh     = xcd * 6 + (slot >> 6);
    const int qchunk = slot & 63;
    const int b_     = bh / NH;
    const int h      = bh % NH;
    const int q0     = qchunk * 32;

    // per-wave mdd slice (same-wave RAW: no barrier needed)
    const float* mp = amask + (size_t)b_ * SEQ;
    #pragma unroll
    for (int i = 0; i < 8; ++i) {
        const int idx = w * 512 + i * 64 + lane;
        mdd[idx] = (__bf16)fmaf(mp[idx], MASK_L2, -MASK_L2);
    }

    // Q as B-operand: B[k=16*dstep+8*hi+j][q=n32]
    const __bf16* Qrow = Qw + ((size_t)bh * SEQ + q0 + n32) * HD + 8 * hi;
    bf16x8 qf[4];
    #pragma unroll
    for (int d = 0; d < 4; ++d) qf[d] = load_bf16x8(Qrow + d * 16);

    bf16x8 qone;
    #pragma unroll
    for (int j = 0; j < 8; ++j) qone[j] = (__bf16)0.0f;
    if (hi == 0) qone[0] = (__bf16)1.0f;   // B[k=0][q] = 1

    const __bf16* kfb_ = Kf + (size_t)bh * SEQ * HD + (size_t)lane * 8;
    const __bf16* vfb_ = Vf + (size_t)bh * SEQ * HD + (size_t)lane * 8;

    f32x16 o0 = {0,0,0,0,0,0,0,0,0,0,0,0,0,0,0,0};
    f32x16 o1 = {0,0,0,0,0,0,0,0,0,0,0,0,0,0,0,0};
    float lsl = 0.f;

    const int kstart = w * 512;
    for (int it = 0; it < 8; ++it) {
        const int kb = kstart + it * 64;
        const size_t foff = (size_t)(kb >> 6) * 4096;

        // all 16 loads issued up front; TLP + MFMA issue hides latency
        bf16x8 kfa[4], kfb[4], vf0[4], vf1[4];
        #pragma unroll
        for (int d = 0; d < 4; ++d) {
            kfa[d] = load_bf16x8(kfb_ + foff + (size_t)(2 * d) * 512);
            kfb[d] = load_bf16x8(kfb_ + foff + (size_t)(2 * d + 1) * 512);
        }
        #pragma unroll
        for (int c = 0; c < 4; ++c) {
            vf0[c] = load_bf16x8(vfb_ + foff + (size_t)(2 * c) * 512);
            vf1[c] = load_bf16x8(vfb_ + foff + (size_t)(2 * c + 1) * 512);
        }

        bf16x8 maa, mab;
        #pragma unroll
        for (int j = 0; j < 8; ++j) { maa[j] = (__bf16)0.0f; mab[j] = (__bf16)0.0f; }
        maa[0] = mdd[kb + n32];
        mab[0] = mdd[kb + 32 + n32];

        // S^T (log2 domain) + mask via rank-1 MFMA
        f32x16 sa = {0,0,0,0,0,0,0,0,0,0,0,0,0,0,0,0};
        f32x16 sb = {0,0,0,0,0,0,0,0,0,0,0,0,0,0,0,0};
        #pragma unroll
        for (int d = 0; d < 4; ++d) {
            sa = __builtin_amdgcn_mfma_f32_32x32x16_bf16(kfa[d], qf[d], sa, 0, 0, 0);
            sb = __builtin_amdgcn_mfma_f32_32x32x16_bf16(kfb[d], qf[d], sb, 0, 0, 0);
        }
        sa = __builtin_amdgcn_mfma_f32_32x32x16_bf16(maa, qone, sa, 0, 0, 0);
        sb = __builtin_amdgcn_mfma_f32_32x32x16_bf16(mab, qone, sb, 0, 0, 0);

        // exp2 + scalar lsum + direct pack (sigma baked into Vf: reg r of
        // each 8-reg group IS B-slot j=r; no cross-lane exchange)
        bf16x8 P[4];
        #pragma unroll
        for (int half = 0; half < 2; ++half) {
            const f32x16& s = half ? sb : sa;
            float p[16];
            #pragma unroll
            for (int r = 0; r < 16; ++r) { p[r] = hw_exp2(s[r]); lsl += p[r]; }
            u32x4 B0, B1;
            #pragma unroll
            for (int i = 0; i < 4; ++i) {
                B0[i] = pack_bf16(p[2 * i],     p[2 * i + 1]);
                B1[i] = pack_bf16(p[8 + 2 * i], p[8 + 2 * i + 1]);
            }
            P[2 * half]     = __builtin_bit_cast(bf16x8, B0);
            P[2 * half + 1] = __builtin_bit_cast(bf16x8, B1);
        }

        #pragma unroll
        for (int c = 0; c < 4; ++c) {
            o0 = __builtin_amdgcn_mfma_f32_32x32x16_bf16(vf0[c], P[c], o0, 0, 0, 0);
            o1 = __builtin_amdgcn_mfma_f32_32x32x16_bf16(vf1[c], P[c], o1, 0, 0, 0);
        }
    }

    // per-wave partial row sums: q=n32 lives on lanes n32 and n32+32
    const float rs = lsl + __shfl_xor(lsl, 32);

    // stage per-wave partials, then cross-wave combine
    #pragma unroll
    for (int r = 0; r < 16; ++r) {
        const int dl = (r & 3) + 8 * (r >> 2) + 4 * hi;
        et[w][n32][dl]      = o0[r];
        et[w][n32][32 + dl] = o1[r];
    }
    if (lane < 32) lrow[w][n32] = rs;
    __syncthreads();

    const int q  = tid >> 3;
    const int d0 = (tid & 7) * 8;
    const float linv = 1.0f / (lrow[0][q] + lrow[1][q] + lrow[2][q] + lrow[3][q]);
    f32x4 acc0 = {0,0,0,0}, acc1 = {0,0,0,0};
    #pragma unroll
    for (int ww = 0; ww < 4; ++ww) {
        acc0 += *(const f32x4*)&et[ww][q][d0];
        acc1 += *(const f32x4*)&et[ww][q][d0 + 4];
    }
    float* orow = out + ((size_t)(b_ * SEQ + q0 + q)) * NP + h * HD + d0;
    f32x4 r0, r1;
    #pragma unroll
    for (int i = 0; i < 4; ++i) { r0[i] = acc0[i] * linv; r1[i] = acc1[i] * linv; }
    *(f32x4*)(orow)     = r0;
    *(f32x4*)(orow + 4) = r1;
}

extern "C" void kernel_launch(void* const* d_in, const int* in_sizes, int n_in,
                              void* d_out, int out_size, void* d_ws, size_t ws_size,
                              hipStream_t stream) {
    const float* hidden = (const float*)d_in[0];
    const float* amask  = (const float*)d_in[1];
    const float* Wq     = (const float*)d_in[2];
    const float* bq     = (const float*)d_in[3];
    const float* Wk     = (const float*)d_in[4];
    const float* bk     = (const float*)d_in[5];
    const float* Wv     = (const float*)d_in[6];
    const float* bv     = (const float*)d_in[7];
    float* out = (float*)d_out;

    const size_t elems = (size_t)NB * NH * SEQ * HD; // 6,291,456
    __bf16* Qw = (__bf16*)d_ws;
    __bf16* Kf = Qw + elems;
    __bf16* Vf = Kf + elems;

    qkv_kernel<<<dim3(128, 6), 256, 0, stream>>>(
        hidden, Wq, Wk, Wv, bq, bk, bv, Qw, Kf, Vf);

    flash_attn_kernel<<<dim3(3072), 256, 0, stream>>>(
        Qw, Kf, Vf, amask, out);
}

// Round 12
// 166.743 us; speedup vs baseline: 1.1451x; 1.0186x over previous
//
#include <hip/hip_runtime.h>
#include <hip/hip_bf16.h>

#define NH 12
#define HD 64
#define NB 4
#define SEQ 2048
#define NP 768
#define LOG2E 1.44269504f
#define MASK_L2 14426.9504f   // 10000 * log2(e)

typedef __bf16 bf16x8 __attribute__((ext_vector_type(8)));
typedef __bf16 bf16x2 __attribute__((ext_vector_type(2)));
typedef float f32x2 __attribute__((ext_vector_type(2)));
typedef float f32x4 __attribute__((ext_vector_type(4)));
typedef float f32x16 __attribute__((ext_vector_type(16)));
typedef unsigned u32x4 __attribute__((ext_vector_type(4)));

static __device__ __forceinline__ bf16x8 load_bf16x8(const __bf16* p) {
    return *reinterpret_cast<const bf16x8*>(p);
}
static __device__ __forceinline__ float hw_exp2(float x) {
    return __builtin_amdgcn_exp2f(x);
}
// packed f32x2 -> bf16x2 (backend can select v_cvt_pk_bf16_f32 on gfx950)
static __device__ __forceinline__ unsigned cvtpk2(float lo, float hi) {
    f32x2 t; t[0] = lo; t[1] = hi;
    return __builtin_bit_cast(unsigned, __builtin_convertvector(t, bf16x2));
}

// ---------------------------------------------------------------------------
// Kernel 1 (byte-identical to round 11): QKV projection, W transpose fused.
// Vf in SIGMA-PERMUTED key order sigma(8*hi+j) = (j&3)+8*(j>>2)+4*hi.
// ---------------------------------------------------------------------------
__global__ __launch_bounds__(256) void qkv_kernel(
    const float* __restrict__ hidden,
    const float* __restrict__ Wq, const float* __restrict__ Wk,
    const float* __restrict__ Wv,
    const float* __restrict__ bq, const float* __restrict__ bk,
    const float* __restrict__ bv,
    __bf16* __restrict__ Qw, __bf16* __restrict__ Kf, __bf16* __restrict__ Vf)
{
    __shared__ __bf16 wtileT[64][72];   // [c][k]
    __shared__ __bf16 ot[64][72];       // [t][c]

    const int tid  = threadIdx.x;
    const int lane = tid & 63;
    const int w    = tid >> 6;
    const int g    = lane >> 4;
    const int n    = lane & 15;
    const int n32  = lane & 31;
    const int hi   = lane >> 5;

    const int row0 = blockIdx.x * 64;
    const int gi   = blockIdx.y;          // 0..5
    const int b_   = row0 >> 11;
    const int t0   = row0 & (SEQ - 1);
    const int kb64 = t0 >> 6;

    const float* hrow = hidden + (size_t)(row0 + w * 16 + n) * HD + 8 * g;
    f32x4 h0 = *(const f32x4*)(hrow);
    f32x4 h1 = *(const f32x4*)(hrow + 4);
    f32x4 h2 = *(const f32x4*)(hrow + 32);
    f32x4 h3 = *(const f32x4*)(hrow + 36);
    bf16x8 a0, a1;
    #pragma unroll
    for (int j = 0; j < 4; ++j) {
        a0[j]     = (__bf16)h0[j];
        a0[j + 4] = (__bf16)h1[j];
        a1[j]     = (__bf16)h2[j];
        a1[j + 4] = (__bf16)h3[j];
    }

    const int dr   = tid >> 2;        // 0..63 (W row = k)
    const int coff = (tid & 3) * 16;  // 16 consecutive cols

    for (int tt = 0; tt < 6; ++tt) {
        const int tile_id = gi * 6 + tt;       // 0..35
        const int proj    = tile_id / 12;
        const int head    = tile_id % 12;
        const int bh      = b_ * NH + head;
        const float* W    = proj == 0 ? Wq : (proj == 1 ? Wk : Wv);
        const float* bias = proj == 0 ? bq : (proj == 1 ? bk : bv);
        const float qs    = (proj == 0) ? 0.125f * LOG2E : 1.0f;

        const float* wr = W + (size_t)dr * NP + head * 64 + coff;
        f32x4 x0 = *(const f32x4*)(wr);
        f32x4 x1 = *(const f32x4*)(wr + 4);
        f32x4 x2 = *(const f32x4*)(wr + 8);
        f32x4 x3 = *(const f32x4*)(wr + 12);
        #pragma unroll
        for (int i = 0; i < 4; ++i) {
            wtileT[coff + i     ][dr] = (__bf16)(x0[i] * qs);
            wtileT[coff + 4 + i ][dr] = (__bf16)(x1[i] * qs);
            wtileT[coff + 8 + i ][dr] = (__bf16)(x2[i] * qs);
            wtileT[coff + 12 + i][dr] = (__bf16)(x3[i] * qs);
        }
        __syncthreads();   // wtileT ready; also fences prev tile's ot reads

        #pragma unroll
        for (int dt = 0; dt < 4; ++dt) {
            const bf16x8 b0 = *(const bf16x8*)&wtileT[dt * 16 + n][8 * g];
            const bf16x8 b1 = *(const bf16x8*)&wtileT[dt * 16 + n][32 + 8 * g];
            f32x4 acc = {0.f, 0.f, 0.f, 0.f};
            acc = __builtin_amdgcn_mfma_f32_16x16x32_bf16(a0, b0, acc, 0, 0, 0);
            acc = __builtin_amdgcn_mfma_f32_16x16x32_bf16(a1, b1, acc, 0, 0, 0);
            const float bb = bias[head * 64 + dt * 16 + n] * qs;
            #pragma unroll
            for (int r = 0; r < 4; ++r)
                ot[w * 16 + 4 * g + r][dt * 16 + n] = (__bf16)(acc[r] + bb);
        }
        __syncthreads();   // ot complete; wtileT frag reads done

        if (proj == 0) {
            __bf16* dst = Qw + ((size_t)bh * SEQ + t0 + w * 16) * HD;
            const int tr = lane >> 2;
            const int d0 = (lane & 3) * 16;
            *(bf16x8*)(dst + (size_t)tr * HD + d0)     = *(const bf16x8*)&ot[w * 16 + tr][d0];
            *(bf16x8*)(dst + (size_t)tr * HD + d0 + 8) = *(const bf16x8*)&ot[w * 16 + tr][d0 + 8];
        } else if (proj == 1) {
            __bf16* base = Kf + (size_t)bh * SEQ * HD + (size_t)kb64 * 4096;
            #pragma unroll
            for (int sub = 0; sub < 2; ++sub) {
                const bf16x8 fr = *(const bf16x8*)&ot[sub * 32 + n32][w * 16 + 8 * hi];
                *(bf16x8*)(base + (size_t)(w * 2 + sub) * 512 + lane * 8) = fr;
            }
        } else {
            __bf16* base = Vf + (size_t)bh * SEQ * HD + (size_t)kb64 * 4096;
            #pragma unroll
            for (int dsub = 0; dsub < 2; ++dsub) {
                bf16x8 v;
                #pragma unroll
                for (int j = 0; j < 8; ++j)
                    v[j] = ot[w * 16 + ((j & 3) + 8 * (j >> 2) + 4 * hi)][dsub * 32 + n32];
                *(bf16x8*)(base + (size_t)(w * 2 + dsub) * 512 + lane * 8) = v;
            }
        }
    }
}

// ---------------------------------------------------------------------------
// Kernel 2 v11: v10's key-split flash with VALU trims:
//  - cvtpk2 (f32x2 -> bf16x2 convertvector; backend can use v_cvt_pk_bf16_f32)
//  - packed f32x2 lsum (v_pk_add_f32), halved add count
//  - halves interleaved (sa dead before sb computed) to shorten S live
//    ranges and keep them in arch VGPRs (avoid v_accvgpr_read in the loop)
// ---------------------------------------------------------------------------
__global__ __launch_bounds__(256, 3) void flash_attn_kernel(
    const __bf16* __restrict__ Qw, const __bf16* __restrict__ Kf,
    const __bf16* __restrict__ Vf, const float* __restrict__ amask,
    float* __restrict__ out)
{
    __shared__ __align__(16) float et[4][32][68];   // per-wave O^T partials
    __shared__ float lrow[4][32];
    __shared__ __bf16 mdd[SEQ];

    const int tid  = threadIdx.x;
    const int lane = tid & 63;
    const int w    = tid >> 6;
    const int n32  = lane & 31;
    const int hi   = lane >> 5;

    const int bid    = blockIdx.x;        // 3072
    const int xcd    = bid & 7;
    const int slot   = bid >> 3;          // 0..383
    const int bh     = xcd * 6 + (slot >> 6);
    const int qchunk = slot & 63;
    const int b_     = bh / NH;
    const int h      = bh % NH;
    const int q0     = qchunk * 32;

    // per-wave mdd slice (same-wave RAW: no barrier needed)
    const float* mp = amask + (size_t)b_ * SEQ;
    #pragma unroll
    for (int i = 0; i < 8; ++i) {
        const int idx = w * 512 + i * 64 + lane;
        mdd[idx] = (__bf16)fmaf(mp[idx], MASK_L2, -MASK_L2);
    }

    // Q as B-operand: B[k=16*dstep+8*hi+j][q=n32]
    const __bf16* Qrow = Qw + ((size_t)bh * SEQ + q0 + n32) * HD + 8 * hi;
    bf16x8 qf[4];
    #pragma unroll
    for (int d = 0; d < 4; ++d) qf[d] = load_bf16x8(Qrow + d * 16);

    bf16x8 qone;
    #pragma unroll
    for (int j = 0; j < 8; ++j) qone[j] = (__bf16)0.0f;
    if (hi == 0) qone[0] = (__bf16)1.0f;   // B[k=0][q] = 1

    const __bf16* kfb_ = Kf + (size_t)bh * SEQ * HD + (size_t)lane * 8;
    const __bf16* vfb_ = Vf + (size_t)bh * SEQ * HD + (size_t)lane * 8;

    f32x16 o0 = {0,0,0,0,0,0,0,0,0,0,0,0,0,0,0,0};
    f32x16 o1 = {0,0,0,0,0,0,0,0,0,0,0,0,0,0,0,0};
    f32x2 lsl2 = {0.f, 0.f};

    const int kstart = w * 512;
    for (int it = 0; it < 8; ++it) {
        const int kb = kstart + it * 64;
        const size_t foff = (size_t)(kb >> 6) * 4096;

        bf16x8 kfa[4], kfb[4], vf0[4], vf1[4];
        #pragma unroll
        for (int d = 0; d < 4; ++d) {
            kfa[d] = load_bf16x8(kfb_ + foff + (size_t)(2 * d) * 512);
            kfb[d] = load_bf16x8(kfb_ + foff + (size_t)(2 * d + 1) * 512);
        }
        #pragma unroll
        for (int c = 0; c < 4; ++c) {
            vf0[c] = load_bf16x8(vfb_ + foff + (size_t)(2 * c) * 512);
            vf1[c] = load_bf16x8(vfb_ + foff + (size_t)(2 * c + 1) * 512);
        }

        bf16x8 maa, mab;
        #pragma unroll
        for (int j = 0; j < 8; ++j) { maa[j] = (__bf16)0.0f; mab[j] = (__bf16)0.0f; }
        maa[0] = mdd[kb + n32];
        mab[0] = mdd[kb + 32 + n32];

        // ---- half 0: keys kb..kb+31 ----
        f32x16 sa = {0,0,0,0,0,0,0,0,0,0,0,0,0,0,0,0};
        #pragma unroll
        for (int d = 0; d < 4; ++d)
            sa = __builtin_amdgcn_mfma_f32_32x32x16_bf16(kfa[d], qf[d], sa, 0, 0, 0);
        sa = __builtin_amdgcn_mfma_f32_32x32x16_bf16(maa, qone, sa, 0, 0, 0);

        bf16x8 P0, P1;
        {
            float p[16];
            #pragma unroll
            for (int r = 0; r < 16; ++r) p[r] = hw_exp2(sa[r]);
            u32x4 B0, B1;
            #pragma unroll
            for (int i = 0; i < 4; ++i) {
                B0[i] = cvtpk2(p[2 * i],     p[2 * i + 1]);
                B1[i] = cvtpk2(p[8 + 2 * i], p[8 + 2 * i + 1]);
            }
            #pragma unroll
            for (int i = 0; i < 8; ++i) {
                f32x2 t; t[0] = p[2 * i]; t[1] = p[2 * i + 1];
                lsl2 += t;
            }
            P0 = __builtin_bit_cast(bf16x8, B0);
            P1 = __builtin_bit_cast(bf16x8, B1);
        }
        o0 = __builtin_amdgcn_mfma_f32_32x32x16_bf16(vf0[0], P0, o0, 0, 0, 0);
        o1 = __builtin_amdgcn_mfma_f32_32x32x16_bf16(vf1[0], P0, o1, 0, 0, 0);
        o0 = __builtin_amdgcn_mfma_f32_32x32x16_bf16(vf0[1], P1, o0, 0, 0, 0);
        o1 = __builtin_amdgcn_mfma_f32_32x32x16_bf16(vf1[1], P1, o1, 0, 0, 0);

        // ---- half 1: keys kb+32..kb+63 ----
        f32x16 sb = {0,0,0,0,0,0,0,0,0,0,0,0,0,0,0,0};
        #pragma unroll
        for (int d = 0; d < 4; ++d)
            sb = __builtin_amdgcn_mfma_f32_32x32x16_bf16(kfb[d], qf[d], sb, 0, 0, 0);
        sb = __builtin_amdgcn_mfma_f32_32x32x16_bf16(mab, qone, sb, 0, 0, 0);

        bf16x8 P2, P3;
        {
            float p[16];
            #pragma unroll
            for (int r = 0; r < 16; ++r) p[r] = hw_exp2(sb[r]);
            u32x4 B0, B1;
            #pragma unroll
            for (int i = 0; i < 4; ++i) {
                B0[i] = cvtpk2(p[2 * i],     p[2 * i + 1]);
                B1[i] = cvtpk2(p[8 + 2 * i], p[8 + 2 * i + 1]);
            }
            #pragma unroll
            for (int i = 0; i < 8; ++i) {
                f32x2 t; t[0] = p[2 * i]; t[1] = p[2 * i + 1];
                lsl2 += t;
            }
            P2 = __builtin_bit_cast(bf16x8, B0);
            P3 = __builtin_bit_cast(bf16x8, B1);
        }
        o0 = __builtin_amdgcn_mfma_f32_32x32x16_bf16(vf0[2], P2, o0, 0, 0, 0);
        o1 = __builtin_amdgcn_mfma_f32_32x32x16_bf16(vf1[2], P2, o1, 0, 0, 0);
        o0 = __builtin_amdgcn_mfma_f32_32x32x16_bf16(vf0[3], P3, o0, 0, 0, 0);
        o1 = __builtin_amdgcn_mfma_f32_32x32x16_bf16(vf1[3], P3, o1, 0, 0, 0);
    }

    // per-wave partial row sums: q=n32 lives on lanes n32 and n32+32
    float rs = lsl2[0] + lsl2[1];
    rs += __shfl_xor(rs, 32);

    // stage per-wave partials, then cross-wave combine
    #pragma unroll
    for (int r = 0; r < 16; ++r) {
        const int dl = (r & 3) + 8 * (r >> 2) + 4 * hi;
        et[w][n32][dl]      = o0[r];
        et[w][n32][32 + dl] = o1[r];
    }
    if (lane < 32) lrow[w][n32] = rs;
    __syncthreads();

    const int q  = tid >> 3;
    const int d0 = (tid & 7) * 8;
    const float linv = 1.0f / (lrow[0][q] + lrow[1][q] + lrow[2][q] + lrow[3][q]);
    f32x4 acc0 = {0,0,0,0}, acc1 = {0,0,0,0};
    #pragma unroll
    for (int ww = 0; ww < 4; ++ww) {
        acc0 += *(const f32x4*)&et[ww][q][d0];
        acc1 += *(const f32x4*)&et[ww][q][d0 + 4];
    }
    float* orow = out + ((size_t)(b_ * SEQ + q0 + q)) * NP + h * HD + d0;
    f32x4 r0, r1;
    #pragma unroll
    for (int i = 0; i < 4; ++i) { r0[i] = acc0[i] * linv; r1[i] = acc1[i] * linv; }
    *(f32x4*)(orow)     = r0;
    *(f32x4*)(orow + 4) = r1;
}

extern "C" void kernel_launch(void* const* d_in, const int* in_sizes, int n_in,
                              void* d_out, int out_size, void* d_ws, size_t ws_size,
                              hipStream_t stream) {
    const float* hidden = (const float*)d_in[0];
    const float* amask  = (const float*)d_in[1];
    const float* Wq     = (const float*)d_in[2];
    const float* bq     = (const float*)d_in[3];
    const float* Wk     = (const float*)d_in[4];
    const float* bk     = (const float*)d_in[5];
    const float* Wv     = (const float*)d_in[6];
    const float* bv     = (const float*)d_in[7];
    float* out = (float*)d_out;

    const size_t elems = (size_t)NB * NH * SEQ * HD; // 6,291,456
    __bf16* Qw = (__bf16*)d_ws;
    __bf16* Kf = Qw + elems;
    __bf16* Vf = Kf + elems;

    qkv_kernel<<<dim3(128, 6), 256, 0, stream>>>(
        hidden, Wq, Wk, Wv, bq, bk, bv, Qw, Kf, Vf);

    flash_attn_kernel<<<dim3(3072), 256, 0, stream>>>(
        Qw, Kf, Vf, amask, out);
}

// Round 13
// 166.421 us; speedup vs baseline: 1.1473x; 1.0019x over previous
//
#include <hip/hip_runtime.h>
#include <hip/hip_bf16.h>

#define NH 12
#define HD 64
#define NB 4
#define SEQ 2048
#define NP 768
#define LOG2E 1.44269504f
#define MASK_L2 14426.9504f   // 10000 * log2(e)

typedef __bf16 bf16x8 __attribute__((ext_vector_type(8)));
typedef __bf16 bf16x2 __attribute__((ext_vector_type(2)));
typedef float f32x2 __attribute__((ext_vector_type(2)));
typedef float f32x4 __attribute__((ext_vector_type(4)));
typedef float f32x16 __attribute__((ext_vector_type(16)));
typedef unsigned u32x4 __attribute__((ext_vector_type(4)));

static __device__ __forceinline__ bf16x8 load_bf16x8(const __bf16* p) {
    return *reinterpret_cast<const bf16x8*>(p);
}
static __device__ __forceinline__ float hw_exp2(float x) {
    return __builtin_amdgcn_exp2f(x);
}
// packed f32x2 -> bf16x2 (backend can select v_cvt_pk_bf16_f32 on gfx950)
static __device__ __forceinline__ unsigned cvtpk2(float lo, float hi) {
    f32x2 t; t[0] = lo; t[1] = hi;
    return __builtin_bit_cast(unsigned, __builtin_convertvector(t, bf16x2));
}

// ---------------------------------------------------------------------------
// Kernel 1 (byte-identical to round 12): QKV projection, W transpose fused.
// Vf in SIGMA-PERMUTED key order sigma(8*hi+j) = (j&3)+8*(j>>2)+4*hi.
// ---------------------------------------------------------------------------
__global__ __launch_bounds__(256) void qkv_kernel(
    const float* __restrict__ hidden,
    const float* __restrict__ Wq, const float* __restrict__ Wk,
    const float* __restrict__ Wv,
    const float* __restrict__ bq, const float* __restrict__ bk,
    const float* __restrict__ bv,
    __bf16* __restrict__ Qw, __bf16* __restrict__ Kf, __bf16* __restrict__ Vf)
{
    __shared__ __bf16 wtileT[64][72];   // [c][k]
    __shared__ __bf16 ot[64][72];       // [t][c]

    const int tid  = threadIdx.x;
    const int lane = tid & 63;
    const int w    = tid >> 6;
    const int g    = lane >> 4;
    const int n    = lane & 15;
    const int n32  = lane & 31;
    const int hi   = lane >> 5;

    const int row0 = blockIdx.x * 64;
    const int gi   = blockIdx.y;          // 0..5
    const int b_   = row0 >> 11;
    const int t0   = row0 & (SEQ - 1);
    const int kb64 = t0 >> 6;

    const float* hrow = hidden + (size_t)(row0 + w * 16 + n) * HD + 8 * g;
    f32x4 h0 = *(const f32x4*)(hrow);
    f32x4 h1 = *(const f32x4*)(hrow + 4);
    f32x4 h2 = *(const f32x4*)(hrow + 32);
    f32x4 h3 = *(const f32x4*)(hrow + 36);
    bf16x8 a0, a1;
    #pragma unroll
    for (int j = 0; j < 4; ++j) {
        a0[j]     = (__bf16)h0[j];
        a0[j + 4] = (__bf16)h1[j];
        a1[j]     = (__bf16)h2[j];
        a1[j + 4] = (__bf16)h3[j];
    }

    const int dr   = tid >> 2;        // 0..63 (W row = k)
    const int coff = (tid & 3) * 16;  // 16 consecutive cols

    for (int tt = 0; tt < 6; ++tt) {
        const int tile_id = gi * 6 + tt;       // 0..35
        const int proj    = tile_id / 12;
        const int head    = tile_id % 12;
        const int bh      = b_ * NH + head;
        const float* W    = proj == 0 ? Wq : (proj == 1 ? Wk : Wv);
        const float* bias = proj == 0 ? bq : (proj == 1 ? bk : bv);
        const float qs    = (proj == 0) ? 0.125f * LOG2E : 1.0f;

        const float* wr = W + (size_t)dr * NP + head * 64 + coff;
        f32x4 x0 = *(const f32x4*)(wr);
        f32x4 x1 = *(const f32x4*)(wr + 4);
        f32x4 x2 = *(const f32x4*)(wr + 8);
        f32x4 x3 = *(const f32x4*)(wr + 12);
        #pragma unroll
        for (int i = 0; i < 4; ++i) {
            wtileT[coff + i     ][dr] = (__bf16)(x0[i] * qs);
            wtileT[coff + 4 + i ][dr] = (__bf16)(x1[i] * qs);
            wtileT[coff + 8 + i ][dr] = (__bf16)(x2[i] * qs);
            wtileT[coff + 12 + i][dr] = (__bf16)(x3[i] * qs);
        }
        __syncthreads();   // wtileT ready; also fences prev tile's ot reads

        #pragma unroll
        for (int dt = 0; dt < 4; ++dt) {
            const bf16x8 b0 = *(const bf16x8*)&wtileT[dt * 16 + n][8 * g];
            const bf16x8 b1 = *(const bf16x8*)&wtileT[dt * 16 + n][32 + 8 * g];
            f32x4 acc = {0.f, 0.f, 0.f, 0.f};
            acc = __builtin_amdgcn_mfma_f32_16x16x32_bf16(a0, b0, acc, 0, 0, 0);
            acc = __builtin_amdgcn_mfma_f32_16x16x32_bf16(a1, b1, acc, 0, 0, 0);
            const float bb = bias[head * 64 + dt * 16 + n] * qs;
            #pragma unroll
            for (int r = 0; r < 4; ++r)
                ot[w * 16 + 4 * g + r][dt * 16 + n] = (__bf16)(acc[r] + bb);
        }
        __syncthreads();   // ot complete; wtileT frag reads done

        if (proj == 0) {
            __bf16* dst = Qw + ((size_t)bh * SEQ + t0 + w * 16) * HD;
            const int tr = lane >> 2;
            const int d0 = (lane & 3) * 16;
            *(bf16x8*)(dst + (size_t)tr * HD + d0)     = *(const bf16x8*)&ot[w * 16 + tr][d0];
            *(bf16x8*)(dst + (size_t)tr * HD + d0 + 8) = *(const bf16x8*)&ot[w * 16 + tr][d0 + 8];
        } else if (proj == 1) {
            __bf16* base = Kf + (size_t)bh * SEQ * HD + (size_t)kb64 * 4096;
            #pragma unroll
            for (int sub = 0; sub < 2; ++sub) {
                const bf16x8 fr = *(const bf16x8*)&ot[sub * 32 + n32][w * 16 + 8 * hi];
                *(bf16x8*)(base + (size_t)(w * 2 + sub) * 512 + lane * 8) = fr;
            }
        } else {
            __bf16* base = Vf + (size_t)bh * SEQ * HD + (size_t)kb64 * 4096;
            #pragma unroll
            for (int dsub = 0; dsub < 2; ++dsub) {
                bf16x8 v;
                #pragma unroll
                for (int j = 0; j < 8; ++j)
                    v[j] = ot[w * 16 + ((j & 3) + 8 * (j >> 2) + 4 * hi)][dsub * 32 + n32];
                *(bf16x8*)(base + (size_t)(w * 2 + dsub) * 512 + lane * 8) = v;
            }
        }
    }
}

// ---------------------------------------------------------------------------
// Kernel 2 v12: v11's key-split flash + latency restructuring:
//  - __launch_bounds__(256,4): 128-VGPR cap; LDS 39424*4 = 157.7KB fits ->
//    4 resident blocks (16 waves/CU) AND S-tiles stay in arch VGPRs
//  - 1-deep K prefetch: K frags for iter+1 issued at iter top (~900cyc cover)
//  - sa+sb MFMA chains issued back-to-back (10-MFMA burst) so exp(half0)
//    overlaps sb execution; V loads covered by the burst
// ---------------------------------------------------------------------------
__global__ __launch_bounds__(256, 4) void flash_attn_kernel(
    const __bf16* __restrict__ Qw, const __bf16* __restrict__ Kf,
    const __bf16* __restrict__ Vf, const float* __restrict__ amask,
    float* __restrict__ out)
{
    __shared__ __align__(16) float et[4][32][68];   // per-wave O^T partials
    __shared__ float lrow[4][32];
    __shared__ __bf16 mdd[SEQ];

    const int tid  = threadIdx.x;
    const int lane = tid & 63;
    const int w    = tid >> 6;
    const int n32  = lane & 31;
    const int hi   = lane >> 5;

    const int bid    = blockIdx.x;        // 3072
    const int xcd    = bid & 7;
    const int slot   = bid >> 3;          // 0..383
    const int bh     = xcd * 6 + (slot >> 6);
    const int qchunk = slot & 63;
    const int b_     = bh / NH;
    const int h      = bh % NH;
    const int q0     = qchunk * 32;

    // per-wave mdd slice (same-wave RAW: no barrier needed)
    const float* mp = amask + (size_t)b_ * SEQ;
    #pragma unroll
    for (int i = 0; i < 8; ++i) {
        const int idx = w * 512 + i * 64 + lane;
        mdd[idx] = (__bf16)fmaf(mp[idx], MASK_L2, -MASK_L2);
    }

    // Q as B-operand: B[k=16*dstep+8*hi+j][q=n32]
    const __bf16* Qrow = Qw + ((size_t)bh * SEQ + q0 + n32) * HD + 8 * hi;
    bf16x8 qf[4];
    #pragma unroll
    for (int d = 0; d < 4; ++d) qf[d] = load_bf16x8(Qrow + d * 16);

    bf16x8 qone;
    #pragma unroll
    for (int j = 0; j < 8; ++j) qone[j] = (__bf16)0.0f;
    if (hi == 0) qone[0] = (__bf16)1.0f;   // B[k=0][q] = 1

    const __bf16* kfb_ = Kf + (size_t)bh * SEQ * HD + (size_t)lane * 8;
    const __bf16* vfb_ = Vf + (size_t)bh * SEQ * HD + (size_t)lane * 8;

    f32x16 o0 = {0,0,0,0,0,0,0,0,0,0,0,0,0,0,0,0};
    f32x16 o1 = {0,0,0,0,0,0,0,0,0,0,0,0,0,0,0,0};
    f32x2 lsl2 = {0.f, 0.f};

    const int kstart = w * 512;

    // preload K fragments for iter 0
    bf16x8 kca[4], kcb[4];
    {
        const size_t f0 = (size_t)(kstart >> 6) * 4096;
        #pragma unroll
        for (int d = 0; d < 4; ++d) {
            kca[d] = load_bf16x8(kfb_ + f0 + (size_t)(2 * d) * 512);
            kcb[d] = load_bf16x8(kfb_ + f0 + (size_t)(2 * d + 1) * 512);
        }
    }

    for (int it = 0; it < 8; ++it) {
        const int kb = kstart + it * 64;
        const size_t foff = (size_t)(kb >> 6) * 4096;
        const int nkb = (kb + 64) & (SEQ - 1);
        const size_t nfoff = (size_t)(nkb >> 6) * 4096;

        // V for this iter (consumed after the 10-MFMA S burst)
        bf16x8 vf0[4], vf1[4];
        #pragma unroll
        for (int c = 0; c < 4; ++c) {
            vf0[c] = load_bf16x8(vfb_ + foff + (size_t)(2 * c) * 512);
            vf1[c] = load_bf16x8(vfb_ + foff + (size_t)(2 * c + 1) * 512);
        }
        // K for next iter (consumed one full iteration later)
        bf16x8 kna[4], knb[4];
        #pragma unroll
        for (int d = 0; d < 4; ++d) {
            kna[d] = load_bf16x8(kfb_ + nfoff + (size_t)(2 * d) * 512);
            knb[d] = load_bf16x8(kfb_ + nfoff + (size_t)(2 * d + 1) * 512);
        }

        bf16x8 maa, mab;
        #pragma unroll
        for (int j = 0; j < 8; ++j) { maa[j] = (__bf16)0.0f; mab[j] = (__bf16)0.0f; }
        maa[0] = mdd[kb + n32];
        mab[0] = mdd[kb + 32 + n32];

        // S burst: both halves back-to-back (independent chains)
        f32x16 sa = {0,0,0,0,0,0,0,0,0,0,0,0,0,0,0,0};
        f32x16 sb = {0,0,0,0,0,0,0,0,0,0,0,0,0,0,0,0};
        #pragma unroll
        for (int d = 0; d < 4; ++d)
            sa = __builtin_amdgcn_mfma_f32_32x32x16_bf16(kca[d], qf[d], sa, 0, 0, 0);
        sa = __builtin_amdgcn_mfma_f32_32x32x16_bf16(maa, qone, sa, 0, 0, 0);
        #pragma unroll
        for (int d = 0; d < 4; ++d)
            sb = __builtin_amdgcn_mfma_f32_32x32x16_bf16(kcb[d], qf[d], sb, 0, 0, 0);
        sb = __builtin_amdgcn_mfma_f32_32x32x16_bf16(mab, qone, sb, 0, 0, 0);

        // half 0 exp/pack (overlaps sb execution)
        bf16x8 P0, P1;
        {
            float p[16];
            #pragma unroll
            for (int r = 0; r < 16; ++r) p[r] = hw_exp2(sa[r]);
            u32x4 B0, B1;
            #pragma unroll
            for (int i = 0; i < 4; ++i) {
                B0[i] = cvtpk2(p[2 * i],     p[2 * i + 1]);
                B1[i] = cvtpk2(p[8 + 2 * i], p[8 + 2 * i + 1]);
            }
            #pragma unroll
            for (int i = 0; i < 8; ++i) {
                f32x2 t; t[0] = p[2 * i]; t[1] = p[2 * i + 1];
                lsl2 += t;
            }
            P0 = __builtin_bit_cast(bf16x8, B0);
            P1 = __builtin_bit_cast(bf16x8, B1);
        }
        o0 = __builtin_amdgcn_mfma_f32_32x32x16_bf16(vf0[0], P0, o0, 0, 0, 0);
        o1 = __builtin_amdgcn_mfma_f32_32x32x16_bf16(vf1[0], P0, o1, 0, 0, 0);
        o0 = __builtin_amdgcn_mfma_f32_32x32x16_bf16(vf0[1], P1, o0, 0, 0, 0);
        o1 = __builtin_amdgcn_mfma_f32_32x32x16_bf16(vf1[1], P1, o1, 0, 0, 0);

        // half 1 exp/pack (overlaps PV half-0 execution)
        bf16x8 P2, P3;
        {
            float p[16];
            #pragma unroll
            for (int r = 0; r < 16; ++r) p[r] = hw_exp2(sb[r]);
            u32x4 B0, B1;
            #pragma unroll
            for (int i = 0; i < 4; ++i) {
                B0[i] = cvtpk2(p[2 * i],     p[2 * i + 1]);
                B1[i] = cvtpk2(p[8 + 2 * i], p[8 + 2 * i + 1]);
            }
            #pragma unroll
            for (int i = 0; i < 8; ++i) {
                f32x2 t; t[0] = p[2 * i]; t[1] = p[2 * i + 1];
                lsl2 += t;
            }
            P2 = __builtin_bit_cast(bf16x8, B0);
            P3 = __builtin_bit_cast(bf16x8, B1);
        }
        o0 = __builtin_amdgcn_mfma_f32_32x32x16_bf16(vf0[2], P2, o0, 0, 0, 0);
        o1 = __builtin_amdgcn_mfma_f32_32x32x16_bf16(vf1[2], P2, o1, 0, 0, 0);
        o0 = __builtin_amdgcn_mfma_f32_32x32x16_bf16(vf0[3], P3, o0, 0, 0, 0);
        o1 = __builtin_amdgcn_mfma_f32_32x32x16_bf16(vf1[3], P3, o1, 0, 0, 0);

        #pragma unroll
        for (int d = 0; d < 4; ++d) { kca[d] = kna[d]; kcb[d] = knb[d]; }
    }

    // per-wave partial row sums: q=n32 lives on lanes n32 and n32+32
    float rs = lsl2[0] + lsl2[1];
    rs += __shfl_xor(rs, 32);

    // stage per-wave partials, then cross-wave combine
    #pragma unroll
    for (int r = 0; r < 16; ++r) {
        const int dl = (r & 3) + 8 * (r >> 2) + 4 * hi;
        et[w][n32][dl]      = o0[r];
        et[w][n32][32 + dl] = o1[r];
    }
    if (lane < 32) lrow[w][n32] = rs;
    __syncthreads();

    const int q  = tid >> 3;
    const int d0 = (tid & 7) * 8;
    const float linv = 1.0f / (lrow[0][q] + lrow[1][q] + lrow[2][q] + lrow[3][q]);
    f32x4 acc0 = {0,0,0,0}, acc1 = {0,0,0,0};
    #pragma unroll
    for (int ww = 0; ww < 4; ++ww) {
        acc0 += *(const f32x4*)&et[ww][q][d0];
        acc1 += *(const f32x4*)&et[ww][q][d0 + 4];
    }
    float* orow = out + ((size_t)(b_ * SEQ + q0 + q)) * NP + h * HD + d0;
    f32x4 r0, r1;
    #pragma unroll
    for (int i = 0; i < 4; ++i) { r0[i] = acc0[i] * linv; r1[i] = acc1[i] * linv; }
    *(f32x4*)(orow)     = r0;
    *(f32x4*)(orow + 4) = r1;
}

extern "C" void kernel_launch(void* const* d_in, const int* in_sizes, int n_in,
                              void* d_out, int out_size, void* d_ws, size_t ws_size,
                              hipStream_t stream) {
    const float* hidden = (const float*)d_in[0];
    const float* amask  = (const float*)d_in[1];
    const float* Wq     = (const float*)d_in[2];
    const float* bq     = (const float*)d_in[3];
    const float* Wk     = (const float*)d_in[4];
    const float* bk     = (const float*)d_in[5];
    const float* Wv     = (const float*)d_in[6];
    const float* bv     = (const float*)d_in[7];
    float* out = (float*)d_out;

    const size_t elems = (size_t)NB * NH * SEQ * HD; // 6,291,456
    __bf16* Qw = (__bf16*)d_ws;
    __bf16* Kf = Qw + elems;
    __bf16* Vf = Kf + elems;

    qkv_kernel<<<dim3(128, 6), 256, 0, stream>>>(
        hidden, Wq, Wk, Wv, bq, bk, bv, Qw, Kf, Vf);

    flash_attn_kernel<<<dim3(3072), 256, 0, stream>>>(
        Qw, Kf, Vf, amask, out);
}